// Round 6
// baseline (255.778 us; speedup 1.0000x reference)
//
#include <hip/hip_runtime.h>
#include <hip/hip_bf16.h>

typedef __attribute__((ext_vector_type(8))) short short8;
typedef __attribute__((ext_vector_type(4))) float f32x4;

constexpr int NT = 512, NE = 1024, NW = 64, NH = 16;
constexpr int NBT = 2048;      // B*T token rows
constexpr int TT = 32;         // attn t-tile
constexpr int WIN = TT + 64;   // 96 staged window rows
constexpr int GRID = 256, THREADS = 512;

__device__ inline short f2bf(float f) {
    __hip_bfloat16 h = __float2bfloat16(f);
    return __builtin_bit_cast(short, h);
}
__device__ inline float blo(unsigned u) { return __builtin_bit_cast(float, u << 16); }
__device__ inline float bhi(unsigned u) { return __builtin_bit_cast(float, u & 0xffff0000u); }

// grid-wide barrier: all GRID blocks co-resident (cooperative launch)
__device__ inline void gsync(unsigned* cnt, int slot) {
    __syncthreads();
    if (threadIdx.x == 0) {
        __threadfence();                               // release my writes
        atomicAdd(&cnt[slot], 1u);
        while (__hip_atomic_load(&cnt[slot], __ATOMIC_RELAXED,
                                 __HIP_MEMORY_SCOPE_AGENT) < (unsigned)GRID) {}
        __threadfence();                               // acquire: invalidate L1
    }
    __syncthreads();
}

__global__ __launch_bounds__(THREADS)
void mega_kernel(const float* __restrict__ x,
                 const float* __restrict__ Wq, const float* __restrict__ bq,
                 const float* __restrict__ Wv, const float* __restrict__ bv,
                 const float* __restrict__ Wo, const float* __restrict__ bo,
                 float* __restrict__ outp,
                 short* __restrict__ Xb, short* __restrict__ WTa,
                 short* __restrict__ Yb, short* __restrict__ Zb,
                 short* __restrict__ Mb, unsigned* __restrict__ cnt) {
    __shared__ __align__(16) char arena[64 * 1024];
    const int tid = threadIdx.x;
    const int bid = blockIdx.x;
    const int lane = tid & 63, wid = tid >> 6;

    // ============ P0: cast x -> bf16; transpose/cast/perm the 3 weights ====
    {
        // cast x (2M f32): 131072 threads x 16 elems
        const int gid = bid * THREADS + tid;
#pragma unroll
        for (int it = 0; it < 2; it++) {
            size_t base = ((size_t)gid * 2 + it) * 8;
            const float4* p = (const float4*)(x + base);
            float4 a = p[0], b = p[1];
            short8 v;
            v[0] = f2bf(a.x); v[1] = f2bf(a.y); v[2] = f2bf(a.z); v[3] = f2bf(a.w);
            v[4] = f2bf(b.x); v[5] = f2bf(b.y); v[6] = f2bf(b.z); v[7] = f2bf(b.w);
            *(short8*)(Xb + base) = v;
        }
        // transposes: 768 64x64 tiles, 3 per block
        float (*tile)[65] = (float(*)[65])arena;
        const int rl = tid >> 3, cl = (tid & 7) * 8;   // load/store coords
        for (int it = 0; it < 3; it++) {
            int tile_id = bid * 3 + it;
            int mi = tile_id >> 8;                      // matrix 0,1,2
            int rem = tile_id & 255;
            int e0 = (rem >> 4) * 64, j0 = (rem & 15) * 64;
            const float* W = mi == 0 ? Wq : (mi == 1 ? Wv : Wo);
            short* WT = WTa + (size_t)mi * NE * NE;
            __syncthreads();                            // tile reuse guard
            const float4* src = (const float4*)(W + (size_t)(e0 + rl) * NE + j0 + cl);
            float4 a = src[0], b = src[1];
            tile[rl][cl + 0] = a.x; tile[rl][cl + 1] = a.y;
            tile[rl][cl + 2] = a.z; tile[rl][cl + 3] = a.w;
            tile[rl][cl + 4] = b.x; tile[rl][cl + 5] = b.y;
            tile[rl][cl + 6] = b.z; tile[rl][cl + 7] = b.w;
            __syncthreads();
            int jg = j0 + rl;
            int jp = (mi < 2) ? ((jg & 15) * 64 + (jg >> 4)) : jg;  // head-major perm
            short8 ov;
#pragma unroll
            for (int j = 0; j < 8; j++) ov[j] = f2bf(tile[cl + j][rl]);
            *(short8*)(WT + (size_t)jp * NE + e0 + cl) = ov;
        }
    }
    gsync(cnt, 0);

    // ============ P1: QV GEMM — one 128x128 tile/block over N_eff=2048 =====
    {
        short* As = (short*)arena;              // [128][64] swizzled, 16KB
        short* Bs = (short*)(arena + 16384);    // [128][64] swizzled, 16KB
        const int xcd = bid & 7, idx = bid >> 3;
        const int c0 = (((xcd << 1) | (idx & 1))) * 128;   // 0..1920
        const int r0 = (idx >> 1) * 128;
        const int wr = (wid & 1) * 64, wc = (wid >> 1) * 32;

        f32x4 acc[4][2];
#pragma unroll
        for (int m = 0; m < 4; m++)
#pragma unroll
            for (int n = 0; n < 2; n++) acc[m][n] = (f32x4){0.f, 0.f, 0.f, 0.f};

        short8 pfA[2], pfB[2];
        auto load_tiles = [&](int k0) {
#pragma unroll
            for (int rd = 0; rd < 2; rd++) {
                int slot = rd * 8192 + tid * 16;
                int row = slot >> 7;
                int c = ((slot >> 4) & 7) ^ (row & 7);
                pfA[rd] = *(const short8*)(Xb  + (size_t)(r0 + row) * NE + k0 + c * 8);
                pfB[rd] = *(const short8*)(WTa + (size_t)(c0 + row) * NE + k0 + c * 8);
            }
        };
        load_tiles(0);
        for (int k0 = 0; k0 < NE; k0 += 64) {
            __syncthreads();
#pragma unroll
            for (int rd = 0; rd < 2; rd++) {
                *(short8*)(As + (rd * 8192 + tid * 16) / 2) = pfA[rd];
                *(short8*)(Bs + (rd * 8192 + tid * 16) / 2) = pfB[rd];
            }
            __syncthreads();
            if (k0 + 64 < NE) load_tiles(k0 + 64);
#pragma unroll
            for (int kk = 0; kk < 2; kk++) {
                short8 af[4], bf[2];
                const int cidx = kk * 4 + (lane >> 4);
#pragma unroll
                for (int m = 0; m < 4; m++) {
                    int row = wr + m * 16 + (lane & 15);
                    af[m] = *(const short8*)((char*)As + row * 128 + ((cidx ^ (row & 7)) * 16));
                }
#pragma unroll
                for (int n = 0; n < 2; n++) {
                    int row = wc + n * 16 + (lane & 15);
                    bf[n] = *(const short8*)((char*)Bs + row * 128 + ((cidx ^ (row & 7)) * 16));
                }
#pragma unroll
                for (int m = 0; m < 4; m++)
#pragma unroll
                    for (int n = 0; n < 2; n++)
                        acc[m][n] = __builtin_amdgcn_mfma_f32_16x16x32_bf16(af[m], bf[n], acc[m][n], 0, 0, 0);
            }
        }
        const bool isZ = (c0 >= NE);
        short* outT = isZ ? Zb : Yb;
        const float* bias = isZ ? bv : bq;
        const int cb = c0 - (isZ ? NE : 0);
#pragma unroll
        for (int m = 0; m < 4; m++)
#pragma unroll
            for (int n = 0; n < 2; n++) {
                int lc = cb + wc + n * 16 + (lane & 15);
                float bb = bias[(lc & 63) * 16 + (lc >> 6)];
#pragma unroll
                for (int r = 0; r < 4; r++) {
                    int row = r0 + wr + m * 16 + (lane >> 4) * 4 + r;
                    outT[(size_t)row * NE + lc] = f2bf(acc[m][n][r] + bb);
                }
            }
    }
    gsync(cnt, 1);

    // ============ P2: windowed attention — 2 half-blocks x 2 rounds ========
    {
        const int h2 = tid >> 8;          // half-block
        const int ltid = tid & 255;
        const int tl = ltid & (TT - 1);
        const int oct = ltid >> 5;        // 0..7
        char* hb = arena + h2 * 32768;
        short (*KS)[66]  = (short(*)[66])(hb);
        short (*VS)[66]  = (short(*)[66])(hb + 12672);
        short (*SCb)[66] = (short(*)[66])(hb + 25344);
        float (*RED)[16] = (float(*)[16])(hb + 29568);

        for (int round = 0; round < 2; round++) {
            __syncthreads();              // LDS reuse guard
            int u = bid * 4 + round * 2 + h2;       // 0..1023
            int t0 = (u & 15) * TT;
            int h  = (u >> 4) & 15;
            int b  = u >> 8;

            for (int idx2 = ltid; idx2 < WIN * 8; idx2 += 256) {
                int row = idx2 >> 3, c = idx2 & 7;
                int ts = t0 - 32 + row;
                ts = ts < 0 ? 0 : (ts > NT - 1 ? NT - 1 : ts);
                size_t base = ((size_t)b * NT + ts) * NE + h * 64 + c * 8;
                *(short8*)&KS[row][c * 8] = *(const short8*)(Yb + base);
                *(short8*)&VS[row][c * 8] = *(const short8*)(Zb + base);
            }
            __syncthreads();

            float q[64];
            {
                const unsigned* Qr = (const unsigned*)&KS[tl + 32][0];
#pragma unroll
                for (int k2 = 0; k2 < 32; k2++) {
                    unsigned uu = Qr[k2];
                    q[2 * k2] = blo(uu); q[2 * k2 + 1] = bhi(uu);
                }
            }
            float sv[8];
#pragma unroll
            for (int wi = 0; wi < 8; wi++) {
                const unsigned* Kr = (const unsigned*)&KS[tl + oct * 8 + wi][0];
                float a2 = 0.f;
#pragma unroll
                for (int k2 = 0; k2 < 32; k2++) {
                    unsigned uu = Kr[k2];
                    a2 += q[2 * k2] * blo(uu) + q[2 * k2 + 1] * bhi(uu);
                }
                sv[wi] = a2 * 0.03125f;
            }
            float lmax = sv[0];
#pragma unroll
            for (int wi = 1; wi < 8; wi++) lmax = fmaxf(lmax, sv[wi]);
            RED[tl][oct] = lmax;
            __syncthreads();
            float gmax = RED[tl][0];
#pragma unroll
            for (int i = 1; i < 8; i++) gmax = fmaxf(gmax, RED[tl][i]);
            float lsum = 0.f;
#pragma unroll
            for (int wi = 0; wi < 8; wi++) {
                float e = __expf(sv[wi] - gmax);
                SCb[tl][oct * 8 + wi] = f2bf(e);
                lsum += e;
            }
            RED[tl][8 + oct] = lsum;
            __syncthreads();
            float gsum = RED[tl][8];
#pragma unroll
            for (int i = 9; i < 16; i++) gsum += RED[tl][i];

            float oacc[8];
#pragma unroll
            for (int j = 0; j < 8; j++) oacc[j] = 0.f;
            for (int w = 0; w < NW; w++) {
                float p = blo((unsigned)(unsigned short)SCb[tl][w]);
                const unsigned* Vr = (const unsigned*)&VS[tl + w][oct * 8];
#pragma unroll
                for (int j2 = 0; j2 < 4; j2++) {
                    unsigned uu = Vr[j2];
                    oacc[2 * j2]     += p * blo(uu);
                    oacc[2 * j2 + 1] += p * bhi(uu);
                }
            }
            float inv = 1.0f / gsum;
            short8 ov;
#pragma unroll
            for (int j = 0; j < 8; j++) ov[j] = f2bf(oacc[j] * inv);
            *(short8*)(Mb + ((size_t)b * NT + t0 + tl) * NE + h * 64 + oct * 8) = ov;
        }
    }
    gsync(cnt, 2);

    // ============ P3: O GEMM — one 128x64 tile/block (M=2048, N=1024) ======
    {
        short* As = (short*)arena;              // [128][64], 16KB
        short* Bs = (short*)(arena + 16384);    // [64][64], 8KB
        const short* WTo = WTa + 2 * (size_t)NE * NE;
        const int xcd = bid & 7, idx = bid >> 3;
        const int c0 = (((xcd << 1) | (idx & 1))) * 64;    // 0..960
        const int r0 = (idx >> 1) * 128;
        const int wr = (wid & 3) * 32, wc = (wid >> 2) * 32;

        f32x4 acc[2][2];
#pragma unroll
        for (int m = 0; m < 2; m++)
#pragma unroll
            for (int n = 0; n < 2; n++) acc[m][n] = (f32x4){0.f, 0.f, 0.f, 0.f};

        short8 pfA[2], pfB;
        auto load_tiles = [&](int k0) {
#pragma unroll
            for (int rd = 0; rd < 2; rd++) {
                int slot = rd * 8192 + tid * 16;
                int row = slot >> 7;
                int c = ((slot >> 4) & 7) ^ (row & 7);
                pfA[rd] = *(const short8*)(Mb + (size_t)(r0 + row) * NE + k0 + c * 8);
            }
            {
                int slot = tid * 16;
                int row = slot >> 7;
                int c = ((slot >> 4) & 7) ^ (row & 7);
                pfB = *(const short8*)(WTo + (size_t)(c0 + row) * NE + k0 + c * 8);
            }
        };
        load_tiles(0);
        for (int k0 = 0; k0 < NE; k0 += 64) {
            __syncthreads();
#pragma unroll
            for (int rd = 0; rd < 2; rd++)
                *(short8*)(As + (rd * 8192 + tid * 16) / 2) = pfA[rd];
            *(short8*)(Bs + (tid * 16) / 2) = pfB;
            __syncthreads();
            if (k0 + 64 < NE) load_tiles(k0 + 64);
#pragma unroll
            for (int kk = 0; kk < 2; kk++) {
                short8 af[2], bf[2];
                const int cidx = kk * 4 + (lane >> 4);
#pragma unroll
                for (int m = 0; m < 2; m++) {
                    int row = wr + m * 16 + (lane & 15);
                    af[m] = *(const short8*)((char*)As + row * 128 + ((cidx ^ (row & 7)) * 16));
                }
#pragma unroll
                for (int n = 0; n < 2; n++) {
                    int row = wc + n * 16 + (lane & 15);
                    bf[n] = *(const short8*)((char*)Bs + row * 128 + ((cidx ^ (row & 7)) * 16));
                }
#pragma unroll
                for (int m = 0; m < 2; m++)
#pragma unroll
                    for (int n = 0; n < 2; n++)
                        acc[m][n] = __builtin_amdgcn_mfma_f32_16x16x32_bf16(af[m], bf[n], acc[m][n], 0, 0, 0);
            }
        }
#pragma unroll
        for (int m = 0; m < 2; m++)
#pragma unroll
            for (int n = 0; n < 2; n++) {
                int col = c0 + wc + n * 16 + (lane & 15);
                float bb = bo[col];
#pragma unroll
                for (int r = 0; r < 4; r++) {
                    int row = r0 + wr + m * 16 + (lane >> 4) * 4 + r;
                    outp[(size_t)row * NE + col] = acc[m][n][r] + bb;
                }
            }
    }
}

// ---------------------------------------------------------------------------
extern "C" void kernel_launch(void* const* d_in, const int* in_sizes, int n_in,
                              void* d_out, int out_size, void* d_ws, size_t ws_size,
                              hipStream_t stream) {
    const float* x  = (const float*)d_in[0];
    // d_in[1] = position_mask: unused (window gather computed analytically)
    const float* Wq = (const float*)d_in[2];
    const float* bq = (const float*)d_in[3];
    const float* Wv = (const float*)d_in[4];
    const float* bv = (const float*)d_in[5];
    const float* Wo = (const float*)d_in[6];
    const float* bo = (const float*)d_in[7];
    float* outp = (float*)d_out;

    // ws: Xb 4M | WTa 6M (Wq,Wv,Wo) | Yb 4M | Zb 4M | Mb 4M | cnt @24M
    char* wsb = (char*)d_ws;
    short* Xb  = (short*)(wsb);
    short* WTa = (short*)(wsb + (4u << 20));
    short* Yb  = (short*)(wsb + (10u << 20));
    short* Zb  = (short*)(wsb + (14u << 20));
    short* Mb  = (short*)(wsb + (18u << 20));
    unsigned* cnt = (unsigned*)(wsb + (24u << 20));

    hipMemsetAsync(cnt, 0, 4 * sizeof(unsigned), stream);

    void* args[] = {&x, &Wq, &bq, &Wv, &bv, &Wo, &bo, &outp,
                    &Xb, &WTa, &Yb, &Zb, &Mb, &cnt};
    hipLaunchCooperativeKernel((void*)mega_kernel, dim3(GRID), dim3(THREADS),
                               args, 0, stream);
}

// Round 7
// 171.125 us; speedup vs baseline: 1.4947x; 1.4947x over previous
//
#include <hip/hip_runtime.h>
#include <hip/hip_bf16.h>

typedef __attribute__((ext_vector_type(8))) short short8;
typedef __attribute__((ext_vector_type(4))) float f32x4;

constexpr int NB = 4, NT = 512, NE = 1024, NH = 16;
constexpr int NBT = 2048;      // B*T token rows
constexpr int TT = 32;         // attn t-tile

__device__ inline short f2bf(float f) {
    __hip_bfloat16 h = __float2bfloat16(f);
    return __builtin_bit_cast(short, h);
}

// ------- cast+transpose all 3 W: f32 [E][N] -> bf16 [N][E]; Wq/Wv col-perm
// perm: output row jp = (j&15)*64 + (j>>4)   (j = d*16+h -> jp = h*64+d)
__global__ __launch_bounds__(256) void transpose_w_kernel(const float* __restrict__ W0,
                                                          const float* __restrict__ W1,
                                                          const float* __restrict__ W2,
                                                          short* __restrict__ WTall) {
    const float* W = blockIdx.z == 0 ? W0 : (blockIdx.z == 1 ? W1 : W2);
    const bool perm = blockIdx.z < 2;
    short* WT = WTall + (size_t)blockIdx.z * NE * NE;

    __shared__ float tile[64][65];
    const int e0 = blockIdx.y * 64, j0 = blockIdx.x * 64;
    const int el = threadIdx.x & 63, grp = threadIdx.x >> 6;
    for (int i = grp; i < 64; i += 4)
        tile[i][el] = W[(size_t)(e0 + i) * NE + j0 + el];
    __syncthreads();
    for (int it = grp; it < 64; it += 4) {
        int j = j0 + it;
        int jp = perm ? ((j & 15) * 64 + (j >> 4)) : j;
        WT[(size_t)jp * NE + e0 + el] = f2bf(tile[el][it]);
    }
}

// ---------------- MFMA GEMM ------------------------------------------------
// out[r][jp] = sum_e A[r][e] * WT[jp][e] + bias.
// BM x BN tile, BK=64, 4 waves 2x2, reg-staged prefetch, XOR-swizzled LDS.
// A_F32: A read as f32 + inline bf16 cvt.  ZT_DUAL: grid-x spans 2*NE; the
// c0>=NE half computes with SWAPPED mfma operands -> D[jp][token] and writes
// transposed Zt[jp][token] (+bias1).
template <int BM, int BN, int LOG_GX, bool A_F32, bool ZT_DUAL, bool PERM_BIAS, bool OUT_BF16>
__global__ __launch_bounds__(256) void mfma_gemm_kernel(const void* __restrict__ Xv,
                                                        const short* __restrict__ WT,
                                                        const float* __restrict__ bias0,
                                                        const float* __restrict__ bias1,
                                                        void* __restrict__ out0,
                                                        short* __restrict__ outZt) {
    constexpr int MR = BM / 32, NR = BN / 32;
    __shared__ short As[BM * 64];
    __shared__ short Bs[BN * 64];
    const int tid = threadIdx.x;
    const int lane = tid & 63, wid = tid >> 6;

    // bijective XCD swizzle (nwg % 8 == 0)
    const int nwg = (1 << LOG_GX) * gridDim.y;
    const int bid = blockIdx.y * (1 << LOG_GX) + blockIdx.x;
    const int swz = (bid & 7) * (nwg >> 3) + (bid >> 3);
    const int r0 = (swz >> LOG_GX) * BM;
    const int c0 = (swz & ((1 << LOG_GX) - 1)) * BN;
    const int wr = (wid >> 1) * (BM / 2), wc = (wid & 1) * (BN / 2);
    const bool isZ = ZT_DUAL && (c0 >= NE);

    f32x4 acc[MR][NR];
#pragma unroll
    for (int m = 0; m < MR; m++)
#pragma unroll
        for (int n = 0; n < NR; n++) acc[m][n] = (f32x4){0.f, 0.f, 0.f, 0.f};

    short8 pfA[MR], pfB[NR];
    auto load_tiles = [&](int k0) {
#pragma unroll
        for (int rd = 0; rd < MR; rd++) {
            int slot = rd * 4096 + tid * 16;
            int row  = slot >> 7;
            int c    = ((slot >> 4) & 7) ^ (row & 7);
            if (A_F32) {
                const float* xa = (const float*)Xv + (size_t)(r0 + row) * NE + k0 + c * 8;
                float4 a = *(const float4*)xa, b = *(const float4*)(xa + 4);
                short8 v;
                v[0] = f2bf(a.x); v[1] = f2bf(a.y); v[2] = f2bf(a.z); v[3] = f2bf(a.w);
                v[4] = f2bf(b.x); v[5] = f2bf(b.y); v[6] = f2bf(b.z); v[7] = f2bf(b.w);
                pfA[rd] = v;
            } else {
                pfA[rd] = *(const short8*)((const short*)Xv + (size_t)(r0 + row) * NE + k0 + c * 8);
            }
        }
#pragma unroll
        for (int rd = 0; rd < NR; rd++) {
            int slot = rd * 4096 + tid * 16;
            int row  = slot >> 7;
            int c    = ((slot >> 4) & 7) ^ (row & 7);
            pfB[rd] = *(const short8*)(WT + (size_t)(c0 + row) * NE + k0 + c * 8);
        }
    };

    load_tiles(0);
    for (int k0 = 0; k0 < NE; k0 += 64) {
        __syncthreads();
#pragma unroll
        for (int rd = 0; rd < MR; rd++)
            *(short8*)((char*)As + rd * 4096 + tid * 16) = pfA[rd];
#pragma unroll
        for (int rd = 0; rd < NR; rd++)
            *(short8*)((char*)Bs + rd * 4096 + tid * 16) = pfB[rd];
        __syncthreads();
        if (k0 + 64 < NE) load_tiles(k0 + 64);

#pragma unroll
        for (int kk = 0; kk < 2; kk++) {
            short8 af[MR], bf[NR];
            const int cidx = kk * 4 + (lane >> 4);
#pragma unroll
            for (int m = 0; m < MR; m++) {
                int row = wr + m * 16 + (lane & 15);
                af[m] = *(const short8*)((char*)As + row * 128 + ((cidx ^ (row & 7)) * 16));
            }
#pragma unroll
            for (int n = 0; n < NR; n++) {
                int row = wc + n * 16 + (lane & 15);
                bf[n] = *(const short8*)((char*)Bs + row * 128 + ((cidx ^ (row & 7)) * 16));
            }
            if (isZ) {
                // swapped operands: D[jp][token]
#pragma unroll
                for (int m = 0; m < MR; m++)
#pragma unroll
                    for (int n = 0; n < NR; n++)
                        acc[m][n] = __builtin_amdgcn_mfma_f32_16x16x32_bf16(bf[n], af[m], acc[m][n], 0, 0, 0);
            } else {
#pragma unroll
                for (int m = 0; m < MR; m++)
#pragma unroll
                    for (int n = 0; n < NR; n++)
                        acc[m][n] = __builtin_amdgcn_mfma_f32_16x16x32_bf16(af[m], bf[n], acc[m][n], 0, 0, 0);
            }
        }
    }

    if (isZ) {
        // acc[m][n]: C-row = jp-local = wc + n*16 + (lane>>4)*4 + r
        //            C-col = token    = wr + m*16 + (lane&15)
        const int cb = c0 - NE;
        const int tok = r0 + wr + (lane & 15);
#pragma unroll
        for (int m = 0; m < MR; m++)
#pragma unroll
            for (int n = 0; n < NR; n++)
#pragma unroll
                for (int r = 0; r < 4; r++) {
                    int jp = cb + wc + n * 16 + (lane >> 4) * 4 + r;
                    float bb = bias1[(jp & 63) * 16 + (jp >> 6)];
                    outZt[(size_t)jp * NBT + tok + m * 16] = f2bf(acc[m][n][r] + bb);
                }
    } else {
        short* outS = (short*)out0;
        float* outF = (float*)out0;
#pragma unroll
        for (int m = 0; m < MR; m++)
#pragma unroll
            for (int n = 0; n < NR; n++) {
                int lc   = c0 + wc + n * 16 + (lane & 15);
                int bsrc = PERM_BIAS ? ((lc & 63) * 16 + (lc >> 6)) : lc;
                float bb = bias0[bsrc];
#pragma unroll
                for (int r = 0; r < 4; r++) {
                    int row = r0 + wr + m * 16 + (lane >> 4) * 4 + r;
                    float val = acc[m][n][r] + bb;
                    if (OUT_BF16) outS[(size_t)row * NE + lc] = f2bf(val);
                    else          outF[(size_t)row * NE + lc] = val;
                }
            }
    }
}

// ---------------- MFMA windowed attention ----------------------------------
// Y bf16 [BT][NE] head-major (Q and K rows); Zt bf16 [NE][BT] (V transposed).
// Block = (t-tile 32, h, b). S = Q K^T over the 96-row window via MFMA,
// banded softmax, O = P V via MFMA with V^T from Zt. Out Mb[BT][NE].
__global__ __launch_bounds__(256) void attn_kernel(const short* __restrict__ Yb,
                                                   const short* __restrict__ Zt,
                                                   short* __restrict__ Mb) {
    __shared__ __align__(16) short KS[96][64];    // XOR-swizzled 16B chunks
    __shared__ __align__(16) short VT[64][96];    // [d][ws] linear
    __shared__ __align__(16) float SL[32][100];   // scores
    __shared__ __align__(16) short PL[32][104];   // probs bf16, zeroed outside band
    __shared__ float RED[32][17];                 // 0..7 max, 8..15 sum, 16 inv

    const int t0 = blockIdx.x * TT;
    const int h  = blockIdx.y;
    const int b  = blockIdx.z;
    const int tid = threadIdx.x;
    const int lane = tid & 63, wid = tid >> 6;

    // zero PL (banded writes later): 32*104/8 = 416 short8
    for (int u = tid; u < 416; u += 256)
        *(short8*)((short*)PL + u * 8) = (short8){0, 0, 0, 0, 0, 0, 0, 0};

    // stage K (= Y rows, also Q): 96 rows x 8 chunks, XOR-swizzled
    for (int u = tid; u < 768; u += 256) {
        int r = u >> 3, c = u & 7;
        int ts = t0 - 32 + r;
        ts = ts < 0 ? 0 : (ts > NT - 1 ? NT - 1 : ts);
        short8 kv = *(const short8*)(Yb + ((size_t)b * NT + ts) * NE + h * 64 + c * 8);
        *(short8*)&KS[r][(c ^ (r & 7)) * 8] = kv;
    }
    // stage V^T from Zt rows: 64 d-rows x 12 chunks of 8 (ws in [0,96))
    {
        const int d = tid >> 2, cbase = (tid & 3) * 3;
        const short* zr = Zt + (size_t)(h * 64 + d) * NBT + b * NT;
#pragma unroll
        for (int i = 0; i < 3; i++) {
            int ch = cbase + i;
            int s0 = t0 - 32 + ch * 8;
            short8 v;
            if (s0 >= 0 && s0 <= NT - 8) {
                v = *(const short8*)(zr + s0);
            } else {
#pragma unroll
                for (int j = 0; j < 8; j++) {
                    int ss = s0 + j;
                    ss = ss < 0 ? 0 : (ss > NT - 1 ? NT - 1 : ss);
                    v[j] = zr[ss];
                }
            }
            *(short8*)&VT[d][ch * 8] = v;
        }
    }
    __syncthreads();

    // QK^T: wave wid: m-frag mq = wid>>1, n-frags ntrio..+2 (s-cols)
    {
        const int mq = wid >> 1, ntrio = (wid & 1) * 3;
        f32x4 sacc[3];
#pragma unroll
        for (int ni = 0; ni < 3; ni++) sacc[ni] = (f32x4){0.f, 0.f, 0.f, 0.f};
#pragma unroll
        for (int ks = 0; ks < 2; ks++) {
            const int cidx = ks * 4 + (lane >> 4);
            int qrow = 32 + mq * 16 + (lane & 15);
            short8 af = *(const short8*)((char*)KS + qrow * 128 + ((cidx ^ (qrow & 7)) * 16));
#pragma unroll
            for (int ni = 0; ni < 3; ni++) {
                int srow = (ntrio + ni) * 16 + (lane & 15);
                short8 bf = *(const short8*)((char*)KS + srow * 128 + ((cidx ^ (srow & 7)) * 16));
                sacc[ni] = __builtin_amdgcn_mfma_f32_16x16x32_bf16(af, bf, sacc[ni], 0, 0, 0);
            }
        }
#pragma unroll
        for (int ni = 0; ni < 3; ni++)
#pragma unroll
            for (int r = 0; r < 4; r++)
                SL[mq * 16 + (lane >> 4) * 4 + r][(ntrio + ni) * 16 + (lane & 15)] =
                    sacc[ni][r] * 0.03125f;   // 1/sqrt(E)
    }
    __syncthreads();

    // banded softmax: thread (tl, oct) handles w = oct*8..+8, s = tl + w
    {
        const int tl = tid & (TT - 1), oct = tid >> 5;
        float sv[8];
#pragma unroll
        for (int wi = 0; wi < 8; wi++) sv[wi] = SL[tl][tl + oct * 8 + wi];
        float lmax = sv[0];
#pragma unroll
        for (int wi = 1; wi < 8; wi++) lmax = fmaxf(lmax, sv[wi]);
        RED[tl][oct] = lmax;
        __syncthreads();
        float gmax = RED[tl][0];
#pragma unroll
        for (int i = 1; i < 8; i++) gmax = fmaxf(gmax, RED[tl][i]);
        float lsum = 0.f;
#pragma unroll
        for (int wi = 0; wi < 8; wi++) {
            float e = __expf(sv[wi] - gmax);
            PL[tl][tl + oct * 8 + wi] = f2bf(e);
            lsum += e;
        }
        RED[tl][8 + oct] = lsum;
        __syncthreads();
        float gsum = RED[tl][8];
#pragma unroll
        for (int i = 9; i < 16; i++) gsum += RED[tl][i];
        if (oct == 0) RED[tl][16] = 1.0f / gsum;
    }
    __syncthreads();

    // PV: wave wid: m-frag mp = wid>>1 (rows), n-frags npair..+1 (d-cols)
    {
        const int mp = wid >> 1, npair = (wid & 1) * 2;
        f32x4 oacc[2];
#pragma unroll
        for (int ni = 0; ni < 2; ni++) oacc[ni] = (f32x4){0.f, 0.f, 0.f, 0.f};
#pragma unroll
        for (int ks = 0; ks < 3; ks++) {   // K = 96
            int prow = mp * 16 + (lane & 15);
            short8 pa = *(const short8*)((char*)PL + prow * 208 + ks * 64 + (lane >> 4) * 16);
#pragma unroll
            for (int ni = 0; ni < 2; ni++) {
                int d = (npair + ni) * 16 + (lane & 15);
                short8 bv = *(const short8*)((char*)VT + d * 192 + ks * 64 + (lane >> 4) * 16);
                oacc[ni] = __builtin_amdgcn_mfma_f32_16x16x32_bf16(pa, bv, oacc[ni], 0, 0, 0);
            }
        }
#pragma unroll
        for (int ni = 0; ni < 2; ni++) {
            int d = (npair + ni) * 16 + (lane & 15);
#pragma unroll
            for (int r = 0; r < 4; r++) {
                int tl = mp * 16 + (lane >> 4) * 4 + r;
                float inv = RED[tl][16];
                Mb[((size_t)b * NT + t0 + tl) * NE + h * 64 + d] = f2bf(oacc[ni][r] * inv);
            }
        }
    }
}

// ---------------------------------------------------------------------------
extern "C" void kernel_launch(void* const* d_in, const int* in_sizes, int n_in,
                              void* d_out, int out_size, void* d_ws, size_t ws_size,
                              hipStream_t stream) {
    const float* x  = (const float*)d_in[0];
    // d_in[1] = position_mask: unused (window gather computed analytically)
    const float* Wq = (const float*)d_in[2];
    const float* bq = (const float*)d_in[3];
    const float* Wv = (const float*)d_in[4];
    const float* bv = (const float*)d_in[5];
    const float* Wo = (const float*)d_in[6];
    const float* bo = (const float*)d_in[7];
    float* outp = (float*)d_out;

    // ws: WTa 6M (Wq,Wv,Wo) | Yb 4M | Zt 4M | Mb 4M
    char* wsb = (char*)d_ws;
    short* WTa = (short*)(wsb);
    short* Yb  = (short*)(wsb + (6u << 20));
    short* Zt  = (short*)(wsb + (10u << 20));
    short* Mb  = (short*)(wsb + (14u << 20));
    short* WTo = WTa + 2 * (size_t)NE * NE;

    transpose_w_kernel<<<dim3(16, 16, 3), 256, 0, stream>>>(Wq, Wv, Wo, WTa);

    // fused Q/V projection: grid (16,16); Z half writes transposed Zt
    mfma_gemm_kernel<128, 128, 4, true, true, true, true>
        <<<dim3(2 * NE / 128, NBT / 128), 256, 0, stream>>>(x, WTa, bq, bv, Yb, Zt);

    attn_kernel<<<dim3(NT / TT, NH, NB), 256, 0, stream>>>(Yb, Zt, Mb);

    // output projection: 64x128 tile -> grid (8,32)
    mfma_gemm_kernel<64, 128, 3, false, false, false, false>
        <<<dim3(NE / 128, NBT / 64), 256, 0, stream>>>(Mb, WTo, bo, nullptr, (void*)outp, nullptr);
}